// Round 1
// baseline (846.890 us; speedup 1.0000x reference)
//
#include <hip/hip_runtime.h>
#include <cstdint>
#include <cstddef>

// ---------------- problem constants ----------------
#define BB 8
#define SS 4096
#define DI 1024
#define DH 1024
#define MDIM (BB * SS)      // 32768
#define NC 32               // scan chunks per sequence
#define CL 128              // chunk length (NC*CL == SS)

// ---------------- ws layout (bytes) ----------------
static constexpr size_t OFF_XB   = 0;                         // 32768*1024*2 = 64MB bf16 x
static constexpr size_t OFF_WZB  = 67108864;                  // 2MB
static constexpr size_t OFF_WHB  = OFF_WZB + 2097152;         // 2MB
static constexpr size_t OFF_LOGC = OFF_WHB + 2097152;         // 128MB fp32
static constexpr size_t OFF_CLA  = OFF_LOGC + 134217728;      // 1MB
static constexpr size_t OFF_CLB  = OFF_CLA + 1048576;         // 1MB
static constexpr size_t OFF_CAR  = OFF_CLB + 1048576;         // 1MB
// total ~199MB

typedef __bf16 bf16;
typedef short short8 __attribute__((ext_vector_type(8)));   // 8 bf16 in 4 VGPRs
typedef float f4 __attribute__((ext_vector_type(4)));
typedef float f32x8 __attribute__((ext_vector_type(8)));
typedef bf16 bf16x8 __attribute__((ext_vector_type(8)));

// ---------------- fp32 -> bf16 conversion ----------------
__global__ void convert_kernel(const float* __restrict__ x, const float* __restrict__ wz,
                               const float* __restrict__ wh,
                               bf16* __restrict__ xb, bf16* __restrict__ wzb, bf16* __restrict__ whb) {
    size_t i = ((size_t)blockIdx.x * 256 + threadIdx.x) * 8;
    const float* src; bf16* dst; size_t off;
    if (i < 33554432u) { src = x; dst = xb; off = i; }
    else if (i < 33554432u + 1048576u) { src = wz; dst = wzb; off = i - 33554432u; }
    else { src = wh; dst = whb; off = i - 34603008u; }
    f32x8 v = *(const f32x8*)(src + off);
    bf16x8 o = __builtin_convertvector(v, bf16x8);
    *(bf16x8*)(dst + off) = o;
}

// ---------------- async global->LDS (16B per lane) ----------------
__device__ __forceinline__ void gload_lds16(const void* g, void* l) {
    __builtin_amdgcn_global_load_lds((const __attribute__((address_space(1))) void*)g,
                                     (__attribute__((address_space(3))) void*)l, 16, 0, 0);
}

// stable softplus
__device__ __forceinline__ float splus(float v) {
    return fmaxf(v, 0.f) + log1pf(__expf(-fabsf(v)));
}

// ---------------- dual GEMM + fused gate epilogue ----------------
// out[m,n] = sum_k A[m,k]*W[n,k]  for W in {Wz, Wh}; both use the same A tile.
// logc = -softplus(k); logb = logsigmoid(k) + log_g(pre)  -> logb goes to d_out (scratch reuse)
__global__ __launch_bounds__(256, 2)
void gemm_dual(const bf16* __restrict__ A, const bf16* __restrict__ Wz, const bf16* __restrict__ Wh,
               const float* __restrict__ bz, const float* __restrict__ bh,
               float* __restrict__ logc, float* __restrict__ logb) {
    __shared__ bf16 sA[128 * 32];   // 8KB, row-major m x k (64B rows)
    __shared__ bf16 sBz[128 * 32];  // n x k
    __shared__ bf16 sBh[128 * 32];

    const int t = threadIdx.x;
    const int bid = blockIdx.x;
    const int m0 = (bid >> 3) * 128;
    const int n0 = (bid & 7) * 128;
    const int lane = t & 63;
    const int w = t >> 6;
    const int mw = (w >> 1) * 64;
    const int nw = (w & 1) * 64;
    const int col16 = lane & 15;
    const int quad = lane >> 4;

    f4 accz[4][4], acch[4][4];
#pragma unroll
    for (int i = 0; i < 4; i++)
#pragma unroll
        for (int j = 0; j < 4; j++) { accz[i][j] = (f4)(0.f); acch[i][j] = (f4)(0.f); }

    const int rowL = t >> 2;          // 0..63: tile row of this thread's 16B chunk
    const int colb = (t & 3) * 16;    // byte offset within 64B row
    const int ldsoff = t * 16;        // linear LDS byte slot (wave-uniform base + lane*16)

    for (int k0 = 0; k0 < DI; k0 += 32) {
        const char* gA0 = (const char*)(A + (size_t)(m0 + rowL) * DI + k0) + colb;
        const char* gA1 = (const char*)(A + (size_t)(m0 + 64 + rowL) * DI + k0) + colb;
        const char* gz0 = (const char*)(Wz + (size_t)(n0 + rowL) * DI + k0) + colb;
        const char* gz1 = (const char*)(Wz + (size_t)(n0 + 64 + rowL) * DI + k0) + colb;
        const char* gh0 = (const char*)(Wh + (size_t)(n0 + rowL) * DI + k0) + colb;
        const char* gh1 = (const char*)(Wh + (size_t)(n0 + 64 + rowL) * DI + k0) + colb;
        gload_lds16(gA0, (char*)sA + ldsoff);
        gload_lds16(gA1, (char*)sA + 4096 + ldsoff);
        gload_lds16(gz0, (char*)sBz + ldsoff);
        gload_lds16(gz1, (char*)sBz + 4096 + ldsoff);
        gload_lds16(gh0, (char*)sBh + ldsoff);
        gload_lds16(gh1, (char*)sBh + 4096 + ldsoff);
        __syncthreads();   // drains vmcnt (global_load_lds) + barrier

        short8 af[4], bzf[4], bhf[4];
#pragma unroll
        for (int i = 0; i < 4; i++)
            af[i] = *(const short8*)(sA + (mw + 16 * i + col16) * 32 + quad * 8);
#pragma unroll
        for (int j = 0; j < 4; j++) {
            bzf[j] = *(const short8*)(sBz + (nw + 16 * j + col16) * 32 + quad * 8);
            bhf[j] = *(const short8*)(sBh + (nw + 16 * j + col16) * 32 + quad * 8);
        }
#pragma unroll
        for (int i = 0; i < 4; i++)
#pragma unroll
            for (int j = 0; j < 4; j++) {
                accz[i][j] = __builtin_amdgcn_mfma_f32_16x16x32_bf16(af[i], bzf[j], accz[i][j], 0, 0, 0);
                acch[i][j] = __builtin_amdgcn_mfma_f32_16x16x32_bf16(af[i], bhf[j], acch[i][j], 0, 0, 0);
            }
        __syncthreads();
    }

    // epilogue: bias + gate math, write logc (ws) and logb (d_out)
#pragma unroll
    for (int j = 0; j < 4; j++) {
        const int cg = n0 + nw + 16 * j + col16;
        const float bzv = bz[cg];
        const float bhv = bh[cg];
#pragma unroll
        for (int i = 0; i < 4; i++) {
#pragma unroll
            for (int r = 0; r < 4; r++) {
                const int rg = m0 + mw + 16 * i + quad * 4 + r;
                float kv = accz[i][j][r] + bzv;
                float pv = acch[i][j][r] + bhv;
                float spk = splus(kv);
                float lc = -spk;              // log(1-z)
                float lz = kv - spk;          // log z  (= logsigmoid(k))
                float lg = (pv >= 0.f) ? __logf(pv + 0.5f) : (pv - splus(pv));
                size_t idx = (size_t)rg * DH + cg;
                logc[idx] = lc;
                logb[idx] = lz + lg;
            }
        }
    }
}

// ---------------- log-space chunked scan ----------------
__device__ __forceinline__ float laddexp(float x, float y) {
    float m = fmaxf(x, y);
    return m + log1pf(__expf(-fabsf(x - y)));
}

// pass 1: per-(b,h,chunk) affine-map composite (la = sum logc, lb = fold)
__global__ void scan_pass1(const float* __restrict__ logc, const float* __restrict__ logb,
                           float* __restrict__ cla, float* __restrict__ clb) {
    const int h = (blockIdx.x & 3) * 256 + threadIdx.x;
    const int c = (blockIdx.x >> 2) & 31;
    const int b = blockIdx.x >> 7;
    size_t base = ((size_t)b * SS + (size_t)c * CL) * DH + h;
    float la = logc[base];
    float lb = logb[base];
#pragma unroll 4
    for (int tt = 1; tt < CL; tt++) {
        size_t idx = base + (size_t)tt * DH;
        float lc = logc[idx];
        float lbt = logb[idx];
        la += lc;
        lb = laddexp(lb + lc, lbt);
    }
    const int ci = (b * NC + c) * DH + h;
    cla[ci] = la;
    clb[ci] = lb;
}

// pass 2: sequential scan over chunk summaries -> per-chunk carry-in
__global__ void scan_pass2(const float* __restrict__ cla, const float* __restrict__ clb,
                           float* __restrict__ car) {
    const int tid = blockIdx.x * 256 + threadIdx.x;  // 0..8191
    const int b = tid >> 10;
    const int h = tid & 1023;
    float carry = -0.69314718055994531f;  // log(0.5) = log h0
#pragma unroll
    for (int c = 0; c < NC; c++) {
        const int ci = (b * NC + c) * DH + h;
        car[ci] = carry;
        carry = laddexp(carry + cla[ci], clb[ci]);
    }
}

// pass 3: apply within chunk, write h = exp(log state). io = logb in / h out (in-place).
__global__ void scan_pass3(const float* __restrict__ logc, float* __restrict__ io,
                           const float* __restrict__ car) {
    const int h = (blockIdx.x & 3) * 256 + threadIdx.x;
    const int c = (blockIdx.x >> 2) & 31;
    const int b = blockIdx.x >> 7;
    size_t base = ((size_t)b * SS + (size_t)c * CL) * DH + h;
    float lh = car[(b * NC + c) * DH + h];
#pragma unroll 4
    for (int tt = 0; tt < CL; tt++) {
        size_t idx = base + (size_t)tt * DH;
        float lc = logc[idx];
        float lbt = io[idx];
        lh = laddexp(lh + lc, lbt);
        io[idx] = __expf(lh);
    }
}

// ---------------- launch ----------------
extern "C" void kernel_launch(void* const* d_in, const int* in_sizes, int n_in,
                              void* d_out, int out_size, void* d_ws, size_t ws_size,
                              hipStream_t stream) {
    const float* x  = (const float*)d_in[0];
    const float* Wz = (const float*)d_in[1];
    const float* bz = (const float*)d_in[2];
    const float* Wh = (const float*)d_in[3];
    const float* bh = (const float*)d_in[4];

    char* ws = (char*)d_ws;
    bf16* xb   = (bf16*)(ws + OFF_XB);
    bf16* wzb  = (bf16*)(ws + OFF_WZB);
    bf16* whb  = (bf16*)(ws + OFF_WHB);
    float* logc = (float*)(ws + OFF_LOGC);
    float* cla  = (float*)(ws + OFF_CLA);
    float* clb  = (float*)(ws + OFF_CLB);
    float* car  = (float*)(ws + OFF_CAR);
    float* out  = (float*)d_out;   // holds logb between GEMM and pass3, then final h

    // 1) fp32 -> bf16 (x, Wz, Wh): (33554432 + 2*1048576)/8/256 = 17408 blocks
    convert_kernel<<<17408, 256, 0, stream>>>(x, Wz, Wh, xb, wzb, whb);

    // 2) dual GEMM + fused gate epilogue: (32768/128)*(1024/128) = 2048 blocks
    gemm_dual<<<2048, 256, 0, stream>>>(xb, wzb, whb, bz, bh, logc, out);

    // 3) chunked log-space scan
    scan_pass1<<<BB * NC * (DH / 256), 256, 0, stream>>>(logc, out, cla, clb);
    scan_pass2<<<(BB * DH) / 256, 256, 0, stream>>>(cla, clb, car);
    scan_pass3<<<BB * NC * (DH / 256), 256, 0, stream>>>(logc, out, car);
}

// Round 2
// 617.355 us; speedup vs baseline: 1.3718x; 1.3718x over previous
//
#include <hip/hip_runtime.h>
#include <cstdint>
#include <cstddef>

// ---------------- problem constants ----------------
#define BB 8
#define SS 4096
#define DI 1024
#define DH 1024
#define MDIM (BB * SS)      // 32768
#define NC 64               // scan chunks per sequence
#define CL 64               // chunk length (NC*CL == SS)

// ---------------- ws layout (bytes) ----------------
// Phase A (convert + GEMMs): xb @0 (64MB), wzb, whb, k-buffer @68MB (128MB)
// Phase B (scan): cla/clb/car overlay the dead xb region @0
static constexpr size_t OFF_XB   = 0;                         // 64MB bf16 x
static constexpr size_t OFF_WZB  = 67108864;                  // 2MB
static constexpr size_t OFF_WHB  = OFF_WZB + 2097152;         // 2MB
static constexpr size_t OFF_K    = OFF_WHB + 2097152;         // 128MB fp32 gate preact k
static constexpr size_t OFF_CLA  = 0;                         // 2MB (overlay, post-GEMM)
static constexpr size_t OFF_CLB  = 2097152;                   // 2MB
static constexpr size_t OFF_CAR  = 4194304;                   // 2MB
// total = 196MB

typedef __bf16 bf16;
typedef short short8 __attribute__((ext_vector_type(8)));   // 8 bf16 in 4 VGPRs
typedef float f4 __attribute__((ext_vector_type(4)));
typedef float f32x8 __attribute__((ext_vector_type(8)));
typedef bf16 bf16x8 __attribute__((ext_vector_type(8)));

// ---------------- fp32 -> bf16 conversion ----------------
__global__ void convert_kernel(const float* __restrict__ x, const float* __restrict__ wz,
                               const float* __restrict__ wh,
                               bf16* __restrict__ xb, bf16* __restrict__ wzb, bf16* __restrict__ whb) {
    size_t i = ((size_t)blockIdx.x * 256 + threadIdx.x) * 8;
    const float* src; bf16* dst; size_t off;
    if (i < 33554432u) { src = x; dst = xb; off = i; }
    else if (i < 33554432u + 1048576u) { src = wz; dst = wzb; off = i - 33554432u; }
    else { src = wh; dst = whb; off = i - 34603008u; }
    f32x8 v = *(const f32x8*)(src + off);
    bf16x8 o = __builtin_convertvector(v, bf16x8);
    *(bf16x8*)(dst + off) = o;
}

// ---------------- async global->LDS (16B per lane) ----------------
__device__ __forceinline__ void gload_lds16(const void* g, void* l) {
    __builtin_amdgcn_global_load_lds((const __attribute__((address_space(1))) void*)g,
                                     (__attribute__((address_space(3))) void*)l, 16, 0, 0);
}

// ---------------- m97-shaped single GEMM, raw output + bias ----------------
// out[m,n] = sum_k A[m,k]*W[n,k] + bias[n]
__global__ __launch_bounds__(256)
void gemm_bias(const bf16* __restrict__ A, const bf16* __restrict__ W,
               const float* __restrict__ bias, float* __restrict__ out) {
    __shared__ bf16 sA[128 * 32];   // 8KB, row-major m x k (64B rows)
    __shared__ bf16 sB[128 * 32];   // n x k

    const int t = threadIdx.x;
    const int bid = blockIdx.x;
    const int m0 = (bid >> 3) * 128;
    const int n0 = (bid & 7) * 128;
    const int lane = t & 63;
    const int w = t >> 6;
    const int mw = (w >> 1) * 64;
    const int nw = (w & 1) * 64;
    const int col16 = lane & 15;
    const int quad = lane >> 4;

    f4 acc[4][4];
#pragma unroll
    for (int i = 0; i < 4; i++)
#pragma unroll
        for (int j = 0; j < 4; j++) acc[i][j] = (f4)(0.f);

    const int rowL = t >> 2;          // 0..63
    const int colb = (t & 3) * 16;    // byte offset within 64B row
    const int ldsoff = t * 16;

    for (int k0 = 0; k0 < DI; k0 += 32) {
        gload_lds16((const char*)(A + (size_t)(m0 + rowL) * DI + k0) + colb, (char*)sA + ldsoff);
        gload_lds16((const char*)(A + (size_t)(m0 + 64 + rowL) * DI + k0) + colb, (char*)sA + 4096 + ldsoff);
        gload_lds16((const char*)(W + (size_t)(n0 + rowL) * DI + k0) + colb, (char*)sB + ldsoff);
        gload_lds16((const char*)(W + (size_t)(n0 + 64 + rowL) * DI + k0) + colb, (char*)sB + 4096 + ldsoff);
        __syncthreads();   // drains vmcnt for global_load_lds

        short8 af[4], bf[4];
#pragma unroll
        for (int i = 0; i < 4; i++)
            af[i] = *(const short8*)(sA + (mw + 16 * i + col16) * 32 + quad * 8);
#pragma unroll
        for (int j = 0; j < 4; j++)
            bf[j] = *(const short8*)(sB + (nw + 16 * j + col16) * 32 + quad * 8);
#pragma unroll
        for (int i = 0; i < 4; i++)
#pragma unroll
            for (int j = 0; j < 4; j++)
                acc[i][j] = __builtin_amdgcn_mfma_f32_16x16x32_bf16(af[i], bf[j], acc[i][j], 0, 0, 0);
        __syncthreads();
    }

    // epilogue: bias add, raw fp32 store (no transcendentals)
#pragma unroll
    for (int j = 0; j < 4; j++) {
        const int cg = n0 + nw + 16 * j + col16;
        const float bv = bias[cg];
#pragma unroll
        for (int i = 0; i < 4; i++) {
#pragma unroll
            for (int r = 0; r < 4; r++) {
                const int rg = m0 + mw + 16 * i + quad * 4 + r;
                out[(size_t)rg * DH + cg] = acc[i][j][r] + bv;
            }
        }
    }
}

// ---------------- gate math (fast hw transcendentals) ----------------
__device__ __forceinline__ void gates(float kv, float pv, float& lc, float& lb) {
    float spk = fmaxf(kv, 0.f) + __logf(1.f + __expf(-fabsf(kv)));  // softplus(k)
    lc = -spk;                                                       // log(1-z)
    float lz = kv - spk;                                             // log z
    float lg = (pv >= 0.f) ? __logf(pv + 0.5f)
                           : (pv - __logf(1.f + __expf(pv)));        // log g(pre)
    lb = lz + lg;
}

__device__ __forceinline__ float laddexp(float x, float y) {
    float m = fmaxf(x, y);
    return m + __logf(1.f + __expf(-fabsf(x - y)));
}

// ---------------- pass 1: per-(b,chunk,h-pair) affine composite ----------------
__global__ void scan_pass1(const float* __restrict__ kbuf, const float* __restrict__ pre,
                           float* __restrict__ cla, float* __restrict__ clb) {
    const int tid = blockIdx.x * 256 + threadIdx.x;  // 0 .. 8*64*512-1
    const int hp = tid & 511;          // h pair
    const int c = (tid >> 9) & 63;
    const int b = tid >> 15;
    size_t base = ((size_t)b * SS + (size_t)c * CL) * DH + hp * 2;

    float2 k2 = *(const float2*)(kbuf + base);
    float2 p2 = *(const float2*)(pre + base);
    float la0, lb0, la1, lb1, lc, lbt;
    gates(k2.x, p2.x, la0, lb0);
    gates(k2.y, p2.y, la1, lb1);
#pragma unroll 4
    for (int tt = 1; tt < CL; tt++) {
        size_t idx = base + (size_t)tt * DH;
        k2 = *(const float2*)(kbuf + idx);
        p2 = *(const float2*)(pre + idx);
        gates(k2.x, p2.x, lc, lbt);
        la0 += lc; lb0 = laddexp(lb0 + lc, lbt);
        gates(k2.y, p2.y, lc, lbt);
        la1 += lc; lb1 = laddexp(lb1 + lc, lbt);
    }
    const size_t ci = (size_t)(b * NC + c) * DH + hp * 2;
    *(float2*)(cla + ci) = make_float2(la0, la1);
    *(float2*)(clb + ci) = make_float2(lb0, lb1);
}

// ---------------- pass 2: sequential scan over chunk summaries ----------------
__global__ void scan_pass2(const float* __restrict__ cla, const float* __restrict__ clb,
                           float* __restrict__ car) {
    const int tid = blockIdx.x * 128 + threadIdx.x;  // 0..8191
    const int b = tid >> 10;
    const int h = tid & 1023;
    float carry = -0.69314718055994531f;  // log(0.5) = log h0
#pragma unroll 8
    for (int c = 0; c < NC; c++) {
        const size_t ci = (size_t)(b * NC + c) * DH + h;
        car[ci] = carry;
        carry = laddexp(carry + cla[ci], clb[ci]);
    }
}

// ---------------- pass 3: apply within chunk, h = exp(log state) ----------------
// pre lives in d_out; overwritten in-place with h (read-before-write per element)
__global__ void scan_pass3(const float* __restrict__ kbuf, float* __restrict__ io,
                           const float* __restrict__ car) {
    const int tid = blockIdx.x * 256 + threadIdx.x;
    const int hp = tid & 511;
    const int c = (tid >> 9) & 63;
    const int b = tid >> 15;
    size_t base = ((size_t)b * SS + (size_t)c * CL) * DH + hp * 2;

    const size_t ci = (size_t)(b * NC + c) * DH + hp * 2;
    float2 lh2 = *(const float2*)(car + ci);
    float lh0 = lh2.x, lh1 = lh2.y, lc, lbt;
#pragma unroll 4
    for (int tt = 0; tt < CL; tt++) {
        size_t idx = base + (size_t)tt * DH;
        float2 k2 = *(const float2*)(kbuf + idx);
        float2 p2 = *(const float2*)(io + idx);
        gates(k2.x, p2.x, lc, lbt);
        lh0 = laddexp(lh0 + lc, lbt);
        gates(k2.y, p2.y, lc, lbt);
        lh1 = laddexp(lh1 + lc, lbt);
        *(float2*)(io + idx) = make_float2(__expf(lh0), __expf(lh1));
    }
}

// ---------------- launch ----------------
extern "C" void kernel_launch(void* const* d_in, const int* in_sizes, int n_in,
                              void* d_out, int out_size, void* d_ws, size_t ws_size,
                              hipStream_t stream) {
    const float* x  = (const float*)d_in[0];
    const float* Wz = (const float*)d_in[1];
    const float* bz = (const float*)d_in[2];
    const float* Wh = (const float*)d_in[3];
    const float* bh = (const float*)d_in[4];

    char* ws = (char*)d_ws;
    bf16* xb   = (bf16*)(ws + OFF_XB);
    bf16* wzb  = (bf16*)(ws + OFF_WZB);
    bf16* whb  = (bf16*)(ws + OFF_WHB);
    float* kbuf = (float*)(ws + OFF_K);
    float* cla  = (float*)(ws + OFF_CLA);   // overlays xb (dead after GEMMs)
    float* clb  = (float*)(ws + OFF_CLB);
    float* car  = (float*)(ws + OFF_CAR);
    float* out  = (float*)d_out;            // holds pre between GEMM2 and pass3, then h

    // 1) fp32 -> bf16: (33554432 + 2*1048576)/8/256 = 17408 blocks
    convert_kernel<<<17408, 256, 0, stream>>>(x, Wz, Wh, xb, wzb, whb);

    // 2) two m97-shaped GEMMs: (32768/128)*(1024/128) = 2048 blocks each
    gemm_bias<<<2048, 256, 0, stream>>>(xb, wzb, bz, kbuf);  // gate preact k
    gemm_bias<<<2048, 256, 0, stream>>>(xb, whb, bh, out);   // candidate preact

    // 3) chunked log-space scan (gates recomputed on the fly)
    scan_pass1<<<(BB * NC * 512) / 256, 256, 0, stream>>>(kbuf, out, cla, clb);
    scan_pass2<<<(BB * DH) / 128, 128, 0, stream>>>(cla, clb, car);
    scan_pass3<<<(BB * NC * 512) / 256, 256, 0, stream>>>(kbuf, out, car);
}

// Round 3
// 558.231 us; speedup vs baseline: 1.5171x; 1.1059x over previous
//
#include <hip/hip_runtime.h>
#include <cstdint>
#include <cstddef>

// ---------------- problem constants ----------------
#define BB 8
#define SS 4096
#define DI 1024
#define DH 1024
#define MDIM (BB * SS)      // 32768
#define NC 64               // scan chunks per sequence
#define CL 64               // chunk length (NC*CL == SS)

// ---------------- ws layout (bytes) ----------------
// Phase A: xb @0 (64MB bf16), wzb/whb (2MB each), kbuf/pbuf fp16 (64MB each)
// Phase B (scan): cla/clb/car (2MB each) overlay the dead xb region
static constexpr size_t OFF_XB   = 0;                         // 64MB
static constexpr size_t OFF_WZB  = 67108864;                  // 2MB
static constexpr size_t OFF_WHB  = OFF_WZB + 2097152;         // 2MB
static constexpr size_t OFF_K    = OFF_WHB + 2097152;         // 64MB fp16 gate preact k
static constexpr size_t OFF_P    = OFF_K + 67108864;          // 64MB fp16 candidate preact
static constexpr size_t OFF_CLA  = 0;                         // overlay
static constexpr size_t OFF_CLB  = 2097152;
static constexpr size_t OFF_CAR  = 4194304;
// total = 196MB

typedef __bf16 bf16;
typedef _Float16 fp16;
typedef short short8 __attribute__((ext_vector_type(8)));   // 8 bf16 in 4 VGPRs
typedef float f4 __attribute__((ext_vector_type(4)));
typedef float f32x8 __attribute__((ext_vector_type(8)));
typedef bf16 bf16x8 __attribute__((ext_vector_type(8)));
typedef fp16 h4 __attribute__((ext_vector_type(4)));

// ---------------- fp32 -> bf16 conversion ----------------
__global__ void convert_kernel(const float* __restrict__ x, const float* __restrict__ wz,
                               const float* __restrict__ wh,
                               bf16* __restrict__ xb, bf16* __restrict__ wzb, bf16* __restrict__ whb) {
    size_t i = ((size_t)blockIdx.x * 256 + threadIdx.x) * 8;
    const float* src; bf16* dst; size_t off;
    if (i < 33554432u) { src = x; dst = xb; off = i; }
    else if (i < 33554432u + 1048576u) { src = wz; dst = wzb; off = i - 33554432u; }
    else { src = wh; dst = whb; off = i - 34603008u; }
    f32x8 v = *(const f32x8*)(src + off);
    bf16x8 o = __builtin_convertvector(v, bf16x8);
    *(bf16x8*)(dst + off) = o;
}

// ---------------- async global->LDS (16B per lane) ----------------
__device__ __forceinline__ void gload_lds16(const void* g, void* l) {
    __builtin_amdgcn_global_load_lds((const __attribute__((address_space(1))) void*)g,
                                     (__attribute__((address_space(3))) void*)l, 16, 0, 0);
}

// ---------------- m97-shaped GEMM, fp16 output + bias, XCD-swizzled ----------------
// out[m,n] = (fp16)(sum_k A[m,k]*W[n,k] + bias[n])
__global__ __launch_bounds__(256)
void gemm_bias(const bf16* __restrict__ A, const bf16* __restrict__ W,
               const float* __restrict__ bias, fp16* __restrict__ out) {
    __shared__ bf16 sA[128 * 32];   // 8KB, row-major m x k (64B rows)
    __shared__ bf16 sB[128 * 32];   // n x k

    const int t = threadIdx.x;
    const int bid = blockIdx.x;
    // XCD swizzle: all 8 n-tiles of one m-tile share bid%8 (same XCD under
    // round-robin dispatch) -> A-tile fetched into exactly one per-XCD L2.
    const int grp = bid >> 6;                 // 0..31
    const int n_idx = (bid >> 3) & 7;         // 0..7
    const int m_idx = (grp << 3) | (bid & 7); // 0..255
    const int m0 = m_idx * 128;
    const int n0 = n_idx * 128;
    const int lane = t & 63;
    const int w = t >> 6;
    const int mw = (w >> 1) * 64;
    const int nw = (w & 1) * 64;
    const int col16 = lane & 15;
    const int quad = lane >> 4;

    f4 acc[4][4];
#pragma unroll
    for (int i = 0; i < 4; i++)
#pragma unroll
        for (int j = 0; j < 4; j++) acc[i][j] = (f4)(0.f);

    const int rowL = t >> 2;          // 0..63
    const int colb = (t & 3) * 16;    // byte offset within 64B row
    const int ldsoff = t * 16;

    for (int k0 = 0; k0 < DI; k0 += 32) {
        gload_lds16((const char*)(A + (size_t)(m0 + rowL) * DI + k0) + colb, (char*)sA + ldsoff);
        gload_lds16((const char*)(A + (size_t)(m0 + 64 + rowL) * DI + k0) + colb, (char*)sA + 4096 + ldsoff);
        gload_lds16((const char*)(W + (size_t)(n0 + rowL) * DI + k0) + colb, (char*)sB + ldsoff);
        gload_lds16((const char*)(W + (size_t)(n0 + 64 + rowL) * DI + k0) + colb, (char*)sB + 4096 + ldsoff);
        __syncthreads();   // drains vmcnt for global_load_lds

        short8 af[4], bf[4];
#pragma unroll
        for (int i = 0; i < 4; i++)
            af[i] = *(const short8*)(sA + (mw + 16 * i + col16) * 32 + quad * 8);
#pragma unroll
        for (int j = 0; j < 4; j++)
            bf[j] = *(const short8*)(sB + (nw + 16 * j + col16) * 32 + quad * 8);
#pragma unroll
        for (int i = 0; i < 4; i++)
#pragma unroll
            for (int j = 0; j < 4; j++)
                acc[i][j] = __builtin_amdgcn_mfma_f32_16x16x32_bf16(af[i], bf[j], acc[i][j], 0, 0, 0);
        __syncthreads();
    }

    // epilogue: bias add, fp16 store (no transcendentals)
#pragma unroll
    for (int j = 0; j < 4; j++) {
        const int cg = n0 + nw + 16 * j + col16;
        const float bv = bias[cg];
#pragma unroll
        for (int i = 0; i < 4; i++) {
#pragma unroll
            for (int r = 0; r < 4; r++) {
                const int rg = m0 + mw + 16 * i + quad * 4 + r;
                out[(size_t)rg * DH + cg] = (fp16)(acc[i][j][r] + bv);
            }
        }
    }
}

// ---------------- gate math (fast hw transcendentals) ----------------
__device__ __forceinline__ void gates(float kv, float pv, float& lc, float& lb) {
    float spk = fmaxf(kv, 0.f) + __logf(1.f + __expf(-fabsf(kv)));  // softplus(k)
    lc = -spk;                                                       // log(1-z)
    float lz = kv - spk;                                             // log z
    float lg = (pv >= 0.f) ? __logf(pv + 0.5f)
                           : (pv - __logf(1.f + __expf(pv)));        // log g(pre)
    lb = lz + lg;
}

__device__ __forceinline__ float laddexp(float x, float y) {
    float m = fmaxf(x, y);
    return m + __logf(1.f + __expf(-fabsf(x - y)));
}

// ---------------- pass 1: per-(b,chunk,h-quad) affine composite ----------------
__global__ void scan_pass1(const fp16* __restrict__ kbuf, const fp16* __restrict__ pbuf,
                           float* __restrict__ cla, float* __restrict__ clb) {
    const int tid = blockIdx.x * 256 + threadIdx.x;  // 0 .. 8*64*256-1
    const int hq = tid & 255;          // h quad
    const int c = (tid >> 8) & 63;
    const int b = tid >> 14;
    size_t base = ((size_t)b * SS + (size_t)c * CL) * DH + hq * 4;

    h4 k4 = *(const h4*)(kbuf + base);
    h4 p4 = *(const h4*)(pbuf + base);
    float la[4], lb[4];
#pragma unroll
    for (int q = 0; q < 4; q++) gates((float)k4[q], (float)p4[q], la[q], lb[q]);
#pragma unroll 4
    for (int tt = 1; tt < CL; tt++) {
        size_t idx = base + (size_t)tt * DH;
        k4 = *(const h4*)(kbuf + idx);
        p4 = *(const h4*)(pbuf + idx);
#pragma unroll
        for (int q = 0; q < 4; q++) {
            float lc, lbt;
            gates((float)k4[q], (float)p4[q], lc, lbt);
            la[q] += lc;
            lb[q] = laddexp(lb[q] + lc, lbt);
        }
    }
    const size_t ci = (size_t)(b * NC + c) * DH + hq * 4;
    *(f4*)(cla + ci) = *(f4*)la;
    *(f4*)(clb + ci) = *(f4*)lb;
}

// ---------------- pass 2: sequential scan over chunk summaries ----------------
__global__ void scan_pass2(const float* __restrict__ cla, const float* __restrict__ clb,
                           float* __restrict__ car) {
    const int tid = blockIdx.x * 256 + threadIdx.x;  // 0..8191
    const int b = tid >> 10;
    const int h = tid & 1023;
    float carry = -0.69314718055994531f;  // log(0.5) = log h0
#pragma unroll 8
    for (int c = 0; c < NC; c++) {
        const size_t ci = (size_t)(b * NC + c) * DH + h;
        car[ci] = carry;
        carry = laddexp(carry + cla[ci], clb[ci]);
    }
}

// ---------------- pass 3: apply within chunk, h = exp(log state) ----------------
__global__ void scan_pass3(const fp16* __restrict__ kbuf, const fp16* __restrict__ pbuf,
                           const float* __restrict__ car, float* __restrict__ out) {
    const int tid = blockIdx.x * 256 + threadIdx.x;
    const int hq = tid & 255;
    const int c = (tid >> 8) & 63;
    const int b = tid >> 14;
    size_t base = ((size_t)b * SS + (size_t)c * CL) * DH + hq * 4;

    const size_t ci = (size_t)(b * NC + c) * DH + hq * 4;
    f4 car4 = *(const f4*)(car + ci);
    float lh[4] = {car4[0], car4[1], car4[2], car4[3]};
#pragma unroll 4
    for (int tt = 0; tt < CL; tt++) {
        size_t idx = base + (size_t)tt * DH;
        h4 k4 = *(const h4*)(kbuf + idx);
        h4 p4 = *(const h4*)(pbuf + idx);
        f4 o;
#pragma unroll
        for (int q = 0; q < 4; q++) {
            float lc, lbt;
            gates((float)k4[q], (float)p4[q], lc, lbt);
            lh[q] = laddexp(lh[q] + lc, lbt);
            o[q] = __expf(lh[q]);
        }
        *(f4*)(out + idx) = o;
    }
}

// ---------------- launch ----------------
extern "C" void kernel_launch(void* const* d_in, const int* in_sizes, int n_in,
                              void* d_out, int out_size, void* d_ws, size_t ws_size,
                              hipStream_t stream) {
    const float* x  = (const float*)d_in[0];
    const float* Wz = (const float*)d_in[1];
    const float* bz = (const float*)d_in[2];
    const float* Wh = (const float*)d_in[3];
    const float* bh = (const float*)d_in[4];

    char* ws = (char*)d_ws;
    bf16* xb   = (bf16*)(ws + OFF_XB);
    bf16* wzb  = (bf16*)(ws + OFF_WZB);
    bf16* whb  = (bf16*)(ws + OFF_WHB);
    fp16* kbuf = (fp16*)(ws + OFF_K);
    fp16* pbuf = (fp16*)(ws + OFF_P);
    float* cla  = (float*)(ws + OFF_CLA);   // overlays xb (dead after GEMMs)
    float* clb  = (float*)(ws + OFF_CLB);
    float* car  = (float*)(ws + OFF_CAR);
    float* out  = (float*)d_out;

    // 1) fp32 -> bf16: (33554432 + 2*1048576)/8/256 = 17408 blocks
    convert_kernel<<<17408, 256, 0, stream>>>(x, Wz, Wh, xb, wzb, whb);

    // 2) two m97-shaped GEMMs (XCD-swizzled): 2048 blocks each
    gemm_bias<<<2048, 256, 0, stream>>>(xb, wzb, bz, kbuf);  // gate preact k
    gemm_bias<<<2048, 256, 0, stream>>>(xb, whb, bh, pbuf);  // candidate preact

    // 3) chunked log-space scan (gates recomputed on the fly, fp16 reads)
    scan_pass1<<<(BB * NC * 256) / 256, 256, 0, stream>>>(kbuf, pbuf, cla, clb);
    scan_pass2<<<(BB * DH) / 256, 256, 0, stream>>>(cla, clb, car);
    scan_pass3<<<(BB * NC * 256) / 256, 256, 0, stream>>>(kbuf, pbuf, car, out);
}

// Round 4
// 471.351 us; speedup vs baseline: 1.7967x; 1.1843x over previous
//
#include <hip/hip_runtime.h>
#include <cstdint>
#include <cstddef>

// ---------------- problem constants ----------------
#define BB 8
#define SS 4096
#define DI 1024
#define DH 1024
#define MDIM (BB * SS)      // 32768
#define NC 128              // scan chunks per sequence
#define CL 32               // chunk length (NC*CL == SS)

// ---------------- ws layout (bytes) ----------------
// Phase A: xb @0 (64MB bf16), wzb/whb (2MB each), kbuf/pbuf fp16 (64MB each)
// Phase B (scan): cla/clb/car (4MB each) overlay the dead xb region
static constexpr size_t OFF_XB   = 0;                         // 64MB
static constexpr size_t OFF_WZB  = 67108864;                  // 2MB
static constexpr size_t OFF_WHB  = OFF_WZB + 2097152;         // 2MB
static constexpr size_t OFF_K    = OFF_WHB + 2097152;         // 64MB fp16 gate preact k
static constexpr size_t OFF_P    = OFF_K + 67108864;          // 64MB fp16 candidate preact
static constexpr size_t OFF_CLA  = 0;                         // overlay (4MB)
static constexpr size_t OFF_CLB  = 4194304;                   // 4MB
static constexpr size_t OFF_CAR  = 8388608;                   // 4MB
// total = 196MB

typedef __bf16 bf16;
typedef _Float16 fp16;
typedef short short8 __attribute__((ext_vector_type(8)));   // 8 bf16 in 4 VGPRs
typedef float f4 __attribute__((ext_vector_type(4)));
typedef float f32x8 __attribute__((ext_vector_type(8)));
typedef bf16 bf16x8 __attribute__((ext_vector_type(8)));
typedef fp16 h4 __attribute__((ext_vector_type(4)));

// ---------------- fp32 -> bf16 conversion ----------------
__global__ void convert_kernel(const float* __restrict__ x, const float* __restrict__ wz,
                               const float* __restrict__ wh,
                               bf16* __restrict__ xb, bf16* __restrict__ wzb, bf16* __restrict__ whb) {
    size_t i = ((size_t)blockIdx.x * 256 + threadIdx.x) * 8;
    const float* src; bf16* dst; size_t off;
    if (i < 33554432u) { src = x; dst = xb; off = i; }
    else if (i < 33554432u + 1048576u) { src = wz; dst = wzb; off = i - 33554432u; }
    else { src = wh; dst = whb; off = i - 34603008u; }
    f32x8 v = *(const f32x8*)(src + off);
    bf16x8 o = __builtin_convertvector(v, bf16x8);
    *(bf16x8*)(dst + off) = o;
}

// ---------------- async global->LDS (16B per lane) ----------------
__device__ __forceinline__ void gload_lds16(const void* g, void* l) {
    __builtin_amdgcn_global_load_lds((const __attribute__((address_space(1))) void*)g,
                                     (__attribute__((address_space(3))) void*)l, 16, 0, 0);
}

// ---------------- m97-shaped GEMM, fp16 output + bias, XCD-swizzled ----------------
// Merged launch: blocks [0,2048) compute k = x@Wz^T + bz -> kbuf
//                blocks [2048,4096) compute pre = x@Wh^T + bh -> pbuf
__global__ __launch_bounds__(256)
void gemm_bias2(const bf16* __restrict__ A,
                const bf16* __restrict__ Wz, const bf16* __restrict__ Wh,
                const float* __restrict__ bz, const float* __restrict__ bh,
                fp16* __restrict__ kout, fp16* __restrict__ pout) {
    __shared__ bf16 sA[128 * 32];   // 8KB, row-major m x k (64B rows)
    __shared__ bf16 sB[128 * 32];   // n x k

    const int t = threadIdx.x;
    int bid = blockIdx.x;
    const bf16* W;
    const float* bias;
    fp16* out;
    if (bid < 2048) { W = Wz; bias = bz; out = kout; }
    else            { W = Wh; bias = bh; out = pout; bid -= 2048; }

    // XCD swizzle: all 8 n-tiles of one m-tile share bid%8 (same XCD under
    // round-robin dispatch) -> A-tile fetched into exactly one per-XCD L2.
    const int grp = bid >> 6;                 // 0..31
    const int n_idx = (bid >> 3) & 7;         // 0..7
    const int m_idx = (grp << 3) | (bid & 7); // 0..255
    const int m0 = m_idx * 128;
    const int n0 = n_idx * 128;
    const int lane = t & 63;
    const int w = t >> 6;
    const int mw = (w >> 1) * 64;
    const int nw = (w & 1) * 64;
    const int col16 = lane & 15;
    const int quad = lane >> 4;

    f4 acc[4][4];
#pragma unroll
    for (int i = 0; i < 4; i++)
#pragma unroll
        for (int j = 0; j < 4; j++) acc[i][j] = (f4)(0.f);

    const int rowL = t >> 2;          // 0..63
    const int colb = (t & 3) * 16;    // byte offset within 64B row
    const int ldsoff = t * 16;

    for (int k0 = 0; k0 < DI; k0 += 32) {
        gload_lds16((const char*)(A + (size_t)(m0 + rowL) * DI + k0) + colb, (char*)sA + ldsoff);
        gload_lds16((const char*)(A + (size_t)(m0 + 64 + rowL) * DI + k0) + colb, (char*)sA + 4096 + ldsoff);
        gload_lds16((const char*)(W + (size_t)(n0 + rowL) * DI + k0) + colb, (char*)sB + ldsoff);
        gload_lds16((const char*)(W + (size_t)(n0 + 64 + rowL) * DI + k0) + colb, (char*)sB + 4096 + ldsoff);
        __syncthreads();   // drains vmcnt for global_load_lds

        short8 af[4], bf[4];
#pragma unroll
        for (int i = 0; i < 4; i++)
            af[i] = *(const short8*)(sA + (mw + 16 * i + col16) * 32 + quad * 8);
#pragma unroll
        for (int j = 0; j < 4; j++)
            bf[j] = *(const short8*)(sB + (nw + 16 * j + col16) * 32 + quad * 8);
#pragma unroll
        for (int i = 0; i < 4; i++)
#pragma unroll
            for (int j = 0; j < 4; j++)
                acc[i][j] = __builtin_amdgcn_mfma_f32_16x16x32_bf16(af[i], bf[j], acc[i][j], 0, 0, 0);
        __syncthreads();
    }

    // epilogue: bias add, fp16 store (no transcendentals)
#pragma unroll
    for (int j = 0; j < 4; j++) {
        const int cg = n0 + nw + 16 * j + col16;
        const float bv = bias[cg];
#pragma unroll
        for (int i = 0; i < 4; i++) {
#pragma unroll
            for (int r = 0; r < 4; r++) {
                const int rg = m0 + mw + 16 * i + quad * 4 + r;
                out[(size_t)rg * DH + cg] = (fp16)(acc[i][j][r] + bv);
            }
        }
    }
}

// ---------------- linear-space gates ----------------
// a = 1 - sigmoid(k), b = sigmoid(k) * g(pre); all positive & bounded for this
// input distribution (|k|,|pre| ~< 5), so linear fp32 is stable: a in (0,1)
// contracts, chunk products underflow gracefully to 0 (= history forgotten).
__device__ __forceinline__ void gates_lin(float kv, float pv, float& a, float& b) {
    float ek = __expf(-kv);
    float z = __builtin_amdgcn_rcpf(1.f + ek);     // sigmoid(k); ek=inf -> z=0, a=1
    a = 1.f - z;
    float ep = __expf(-pv);
    float gneg = __builtin_amdgcn_rcpf(1.f + ep);  // sigmoid(pre)
    float g = (pv >= 0.f) ? (pv + 0.5f) : gneg;
    b = z * g;
}

// ---------------- pass 1: per-(b,chunk,h-quad) affine composite ----------------
// composite over chunk: h_out = A*h_in + B, with A = prod a_t, B = fold fma
__global__ void scan_pass1(const fp16* __restrict__ kbuf, const fp16* __restrict__ pbuf,
                           float* __restrict__ cla, float* __restrict__ clb) {
    const int tid = blockIdx.x * 256 + threadIdx.x;  // 0 .. 8*128*256-1
    const int hq = tid & 255;          // h quad
    const int c = (tid >> 8) & 127;
    const int b = tid >> 15;
    size_t base = ((size_t)b * SS + (size_t)c * CL) * DH + hq * 4;

    float A[4] = {1.f, 1.f, 1.f, 1.f};
    float Bc[4] = {0.f, 0.f, 0.f, 0.f};
#pragma unroll 4
    for (int tt = 0; tt < CL; tt++) {
        size_t idx = base + (size_t)tt * DH;
        h4 k4 = *(const h4*)(kbuf + idx);
        h4 p4 = *(const h4*)(pbuf + idx);
#pragma unroll
        for (int q = 0; q < 4; q++) {
            float a, bb;
            gates_lin((float)k4[q], (float)p4[q], a, bb);
            A[q] *= a;
            Bc[q] = fmaf(a, Bc[q], bb);
        }
    }
    const size_t ci = (size_t)(b * NC + c) * DH + hq * 4;
    *(f4*)(cla + ci) = *(f4*)A;
    *(f4*)(clb + ci) = *(f4*)Bc;
}

// ---------------- pass 2: sequential scan over chunk summaries ----------------
__global__ void scan_pass2(const float* __restrict__ cla, const float* __restrict__ clb,
                           float* __restrict__ car) {
    const int tid = blockIdx.x * 256 + threadIdx.x;  // 0..8191
    const int b = tid >> 10;
    const int h = tid & 1023;
    float carry = 0.5f;  // h0
#pragma unroll 8
    for (int c = 0; c < NC; c++) {
        const size_t ci = (size_t)(b * NC + c) * DH + h;
        car[ci] = carry;
        carry = fmaf(cla[ci], carry, clb[ci]);
    }
}

// ---------------- pass 3: apply within chunk, write h ----------------
__global__ void scan_pass3(const fp16* __restrict__ kbuf, const fp16* __restrict__ pbuf,
                           const float* __restrict__ car, float* __restrict__ out) {
    const int tid = blockIdx.x * 256 + threadIdx.x;
    const int hq = tid & 255;
    const int c = (tid >> 8) & 127;
    const int b = tid >> 15;
    size_t base = ((size_t)b * SS + (size_t)c * CL) * DH + hq * 4;

    const size_t ci = (size_t)(b * NC + c) * DH + hq * 4;
    f4 car4 = *(const f4*)(car + ci);
    float h[4] = {car4[0], car4[1], car4[2], car4[3]};
#pragma unroll 4
    for (int tt = 0; tt < CL; tt++) {
        size_t idx = base + (size_t)tt * DH;
        h4 k4 = *(const h4*)(kbuf + idx);
        h4 p4 = *(const h4*)(pbuf + idx);
        f4 o;
#pragma unroll
        for (int q = 0; q < 4; q++) {
            float a, bb;
            gates_lin((float)k4[q], (float)p4[q], a, bb);
            h[q] = fmaf(a, h[q], bb);
            o[q] = h[q];
        }
        *(f4*)(out + idx) = o;
    }
}

// ---------------- launch ----------------
extern "C" void kernel_launch(void* const* d_in, const int* in_sizes, int n_in,
                              void* d_out, int out_size, void* d_ws, size_t ws_size,
                              hipStream_t stream) {
    const float* x  = (const float*)d_in[0];
    const float* Wz = (const float*)d_in[1];
    const float* bz = (const float*)d_in[2];
    const float* Wh = (const float*)d_in[3];
    const float* bh = (const float*)d_in[4];

    char* ws = (char*)d_ws;
    bf16* xb   = (bf16*)(ws + OFF_XB);
    bf16* wzb  = (bf16*)(ws + OFF_WZB);
    bf16* whb  = (bf16*)(ws + OFF_WHB);
    fp16* kbuf = (fp16*)(ws + OFF_K);
    fp16* pbuf = (fp16*)(ws + OFF_P);
    float* cla  = (float*)(ws + OFF_CLA);   // overlays xb (dead after GEMMs)
    float* clb  = (float*)(ws + OFF_CLB);
    float* car  = (float*)(ws + OFF_CAR);
    float* out  = (float*)d_out;

    // 1) fp32 -> bf16: (33554432 + 2*1048576)/8/256 = 17408 blocks
    convert_kernel<<<17408, 256, 0, stream>>>(x, Wz, Wh, xb, wzb, whb);

    // 2) both GEMMs in one launch: 4096 blocks
    gemm_bias2<<<4096, 256, 0, stream>>>(xb, wzb, whb, bz, bh, kbuf, pbuf);

    // 3) chunked linear-space scan (gates recomputed on the fly, fp16 reads)
    scan_pass1<<<(BB * NC * 256) / 256, 256, 0, stream>>>(kbuf, pbuf, cla, clb);
    scan_pass2<<<(BB * DH) / 256, 256, 0, stream>>>(cla, clb, car);
    scan_pass3<<<(BB * NC * 256) / 256, 256, 0, stream>>>(kbuf, pbuf, car, out);
}